// Round 10
// baseline (15901.427 us; speedup 1.0000x reference)
//
#include <hip/hip_runtime.h>

typedef __bf16 bf16x8  __attribute__((ext_vector_type(8)));
typedef float  f32x4   __attribute__((ext_vector_type(4)));

#define MFMA16(a,b,c) __builtin_amdgcn_mfma_f32_16x16x32_bf16((a),(b),(c),0,0,0)

constexpr int BB = 128, TT = 512, II = 512, HH = 1024, OO = 512;
constexpr int TICKS = TT + 4;
// LDS: weights (stage0 80K, else 64K; reserve 80K) + 8 waves x 8KB DMA staging
constexpr int STG_OFF   = 81920;
constexpr int LDS_BYTES = 81920 + 8 * 8192;   // 147456 <= 160K

// -------- workspace layout (bytes), ring depth DD --------
template<int DD> struct WS {
    static constexpr size_t HB      = (size_t)4*DD*BB*HH*2;
    static constexpr size_t FLG_OFF = HB;
    static constexpr size_t FLG     = (size_t)4*TICKS*64*4;
    static constexpr size_t ARR_OFF = FLG_OFF + FLG;
    static constexpr size_t ARR     = (size_t)TICKS*8*64*4;
    static constexpr size_t INV_OFF = ARR_OFF + ARR;
    static constexpr size_t INV     = (size_t)TICKS*8*64;
    static constexpr size_t CE_OFF  = INV_OFF + INV;
    static constexpr size_t IB_OFF  = CE_OFF + 64;
    static constexpr size_t END     = IB_OFF + 9*64;
};

__device__ __forceinline__ float tanh_fast(float v) {
    float e = __expf(2.0f * v);
    return 1.0f - 2.0f / (e + 1.0f);
}

__device__ __forceinline__ bf16x8 cvt8(const float* __restrict__ p) {
    float4 a = *(const float4*)p;
    float4 b = *(const float4*)(p + 4);
    bf16x8 r;
    r[0]=(__bf16)a.x; r[1]=(__bf16)a.y; r[2]=(__bf16)a.z; r[3]=(__bf16)a.w;
    r[4]=(__bf16)b.x; r[5]=(__bf16)b.y; r[6]=(__bf16)b.z; r[7]=(__bf16)b.w;
    return r;
}
__device__ __forceinline__ bf16x8 ldfrag(const __bf16* __restrict__ p) { return *(const bf16x8*)p; }
__device__ __forceinline__ bf16x8 ldfrag(const float* __restrict__ p)  { return cvt8(p); }

// async global->LDS, 16B per lane; LDS dest = wave-uniform base + lane*16
__device__ __forceinline__ void gl_lds16(const void* g, void* l) {
    __builtin_amdgcn_global_load_lds(
        (const __attribute__((address_space(1))) unsigned int*)g,
        (__attribute__((address_space(3))) unsigned int*)l, 16, 0, 0);
}

// write-through system-scope stores (coherent at L3; L2 never dirty)
__device__ __forceinline__ void store_h_wt(__bf16* p, float v) {
    __bf16 b = (__bf16)v;
    unsigned u = *(unsigned short*)&b;
    asm volatile("global_store_short %0, %1, off sc0 sc1" :: "v"(p), "v"(u) : "memory");
}
__device__ __forceinline__ void store_f_wt(float* p, float v) {
    asm volatile("global_store_dword %0, %1, off sc0 sc1" :: "v"(p), "v"(v) : "memory");
}

__device__ __forceinline__ void stage_img(char* dst, const float* __restrict__ W,
                                          int Kdim, int col0, int tid) {
    const int nch = (Kdim / 32) * 64;
    for (int c = tid; c < nch; c += 512) {
        int i  = c >> 6, ln = c & 63;
        int col = col0 + (ln & 15);
        int k0  = i * 32 + ((ln >> 4) << 3);
        bf16x8 v = cvt8(W + (size_t)col * Kdim + k0);
        *(bf16x8*)(dst + (size_t)c * 16) = v;
    }
}

// register-path GEMM (x only; small K)
template<int NITER, int CH, class TA>
__device__ __forceinline__ void gemm1(const TA* __restrict__ ap,
                                      const char* bimg, int lane, f32x4& acc) {
    const char* bp = bimg + (size_t)lane * 16;
    #pragma unroll 1
    for (int c = 0; c < NITER / CH; ++c) {
        bf16x8 B[CH], A[CH];
        #pragma unroll
        for (int j = 0; j < CH; ++j)
            B[j] = *(const bf16x8*)(bp + (size_t)(c*CH + j) * 1024);
        #pragma unroll
        for (int j = 0; j < CH; ++j)
            A[j] = ldfrag(ap + (c*CH + j) * 32);
        #pragma unroll
        for (int j = 0; j < CH; ++j)
            acc = MFMA16(A[j], B[j], acc);
    }
}

// DMA-staged K=1024 GEMM, 1 or 2 streams. Per chunk (64 cols): issue next
// chunk's DMA, counted vmcnt, ds_read fragments, MFMA. wbuf = wave-private 8KB.
template<bool TWO>
__device__ __forceinline__ void gemm_dma(const char* gl0, const char* gl1,
                                         char* wbuf,
                                         const char* img0, const char* img1,
                                         int lane, f32x4& acc0, f32x4& acc1) {
    const int lo = lane * 16;
    asm volatile("s_waitcnt lgkmcnt(0)" ::: "memory");   // prior phase LDS reads done
    gl_lds16(gl0,      wbuf);
    gl_lds16(gl0 + 64, wbuf + 1024);
    if constexpr (TWO) { gl_lds16(gl1, wbuf + 4096); gl_lds16(gl1 + 64, wbuf + 5120); }
    #pragma unroll 1
    for (int kc = 0; kc < 16; ++kc) {
        const int db = (kc & 1) * 2048;
        const int nb = 2048 - db;
        if (kc < 15) {
            asm volatile("s_waitcnt lgkmcnt(0)" ::: "memory");  // nb's old reads retired
            const char* g0 = gl0 + (kc + 1) * 128;
            gl_lds16(g0,      wbuf + nb);
            gl_lds16(g0 + 64, wbuf + nb + 1024);
            if constexpr (TWO) {
                const char* g1 = gl1 + (kc + 1) * 128;
                gl_lds16(g1,      wbuf + 4096 + nb);
                gl_lds16(g1 + 64, wbuf + 4096 + nb + 1024);
                asm volatile("s_waitcnt vmcnt(4)" ::: "memory");
            } else {
                asm volatile("s_waitcnt vmcnt(2)" ::: "memory");
            }
        } else {
            asm volatile("s_waitcnt vmcnt(0)" ::: "memory");
        }
        const size_t kb = (size_t)(kc * 2) * 1024;
        #pragma unroll
        for (int i = 0; i < 2; ++i) {
            bf16x8 a0 = *(const bf16x8*)(wbuf + db + i*1024 + lo);
            bf16x8 b0 = *(const bf16x8*)(img0 + kb + (size_t)i*1024 + lo);
            acc0 = MFMA16(a0, b0, acc0);
            if constexpr (TWO) {
                bf16x8 a1 = *(const bf16x8*)(wbuf + 4096 + db + i*1024 + lo);
                bf16x8 b1 = *(const bf16x8*)(img1 + kb + (size_t)i*1024 + lo);
                acc1 = MFMA16(a1, b1, acc1);
            }
        }
    }
}

template<int DD>
__device__ __forceinline__ void init_barrier(char* wsb, int grp, int tid) {
    __threadfence();
    __syncthreads();
    if (tid == 0) {
        int* c1 = (int*)(wsb + WS<DD>::IB_OFF + (size_t)grp * 64);
        int* c2 = (int*)(wsb + WS<DD>::IB_OFF + 8 * 64);
        int v = __hip_atomic_fetch_add(c1, 1, __ATOMIC_ACQ_REL, __HIP_MEMORY_SCOPE_AGENT);
        if (v == 31)
            __hip_atomic_fetch_add(c2, 1, __ATOMIC_ACQ_REL, __HIP_MEMORY_SCOPE_AGENT);
        while (__hip_atomic_load(c2, __ATOMIC_RELAXED, __HIP_MEMORY_SCOPE_AGENT) < 8)
            __builtin_amdgcn_s_sleep(2);
    }
    __syncthreads();
    __threadfence();
}

template<int DD>
__global__ void __launch_bounds__(512, 1)
rnn_coop(const float* __restrict__ x,
         const float* __restrict__ W_ih0, const float* __restrict__ b_ih0,
         const float* __restrict__ W_hh0, const float* __restrict__ b_hh0,
         const float* __restrict__ W_ih,  const float* __restrict__ b_ih,
         const float* __restrict__ W_hh,  const float* __restrict__ b_hh,
         const float* __restrict__ W_fc,  const float* __restrict__ b_fc,
         float* __restrict__ out, char* __restrict__ wsb)
{
    extern __shared__ char smem[];
    __shared__ int sh_slot, sh_n;

    const int blk = blockIdx.x, tid = threadIdx.x;
    const int wave = tid >> 6, lane = tid & 63;
    const int lrow = lane & 15;
    const int kg8  = (lane >> 4) << 3;
    const int rb   = (lane >> 4) << 2;

    int myxcd;
    asm volatile("s_getreg_b32 %0, hwreg(HW_REG_XCC_ID)" : "=s"(myxcd));
    myxcd &= 7;

    if (tid == 0)
        sh_slot = __hip_atomic_fetch_add((int*)(wsb + WS<DD>::CE_OFF) + myxcd, 1,
                                         __ATOMIC_RELAXED, __HIP_MEMORY_SCOPE_AGENT);

    const int stage = (blk & 7) >> 1;
    const int tile  = (blk >> 3) | ((blk & 1) << 5);
    const int N0    = tile * 16;

    char* img_a  = smem;
    char* img_b;
    char* img_fc = smem + 49152;
    char* wbuf   = smem + STG_OFF + wave * 8192;
    if (stage == 0) {
        img_b = smem + 16384;
        stage_img(img_a, W_ih0, II, N0, tid);
        stage_img(img_b, W_hh0, HH, N0, tid);
        stage_img(img_fc, W_fc, HH, (tile & 31) * 16, tid);
    } else {
        img_b = smem + 32768;
        stage_img(img_a, W_ih + (size_t)(stage-1)*HH*HH, HH, N0, tid);
        stage_img(img_b, W_hh + (size_t)(stage-1)*HH*HH, HH, N0, tid);
    }

    const int bcol = N0 + lrow;
    float bi;
    if (stage == 0) bi = b_ih0[bcol] + b_hh0[bcol];
    else            bi = b_ih[(stage-1)*HH + bcol] + b_hh[(stage-1)*HH + bcol];

    const int fcol  = (tile & 31) * 16 + lrow;
    const int frow0 = (tile >> 5) * 64 + 16 * wave;
    const float fbias = (stage == 0) ? b_fc[fcol] : 0.f;

    const int r0row = 16 * wave + lrow;
    __bf16* hb = (__bf16*)wsb;
    int* flg = (int*)(wsb + WS<DD>::FLG_OFF);
    int* arr = (int*)(wsb + WS<DD>::ARR_OFF);
    const int lco = (lane >> 4) * 16;   // 16B sub-col within 64B row-slice

    __syncthreads();
    init_barrier<DD>(wsb, blk & 7, tid);
    if (tid == 0)
        sh_n = __hip_atomic_load((int*)(wsb + WS<DD>::CE_OFF) + myxcd,
                                 __ATOMIC_RELAXED, __HIP_MEMORY_SCOPE_AGENT);
    __syncthreads();
    const int slot = sh_slot, nloc = sh_n;
    const bool leader = (slot == 0);
    const int sN = (stage < 3) ? stage + 1 : 0;

    for (int tk = 0; tk < TICKS; ++tk) {
        const int rp = (tk - 1) & (DD - 1);
        const int wq = tk & (DD - 1);
        const int t  = tk - stage;
        const bool doH = (t >= 0 && t < TT);
        const bool doF = (stage == 0) && (wave < 4) && (tk >= 4);

        f32x4 acc0 = {0.f,0.f,0.f,0.f};
        f32x4 acc1 = {0.f,0.f,0.f,0.f};

        // x-GEMM is flag-independent: run BEFORE polls (latency overlaps wait)
        if (stage == 0 && doH) {
            const float* xa = x + (size_t)r0row * (TT*II) + (size_t)t * II + kg8;
            gemm1<II/32, 4>(xa, img_a, lane, acc0);
        }

        // ---- protocol (R9-verbatim): arrival, per-XCD inv, dataflow polls ----
        if (tid == 0)
            __hip_atomic_store(arr + ((size_t)tk*8 + myxcd)*64 + slot, 1,
                               __ATOMIC_RELAXED, __HIP_MEMORY_SCOPE_AGENT);
        if (tid < 64) {
            int* invd = (int*)(wsb + WS<DD>::INV_OFF) + ((size_t)tk*8 + myxcd)*16;
            if (leader) {
                const int gk = tk - DD + 1;
                if (gk >= 0) {
                    int* ap = arr + ((size_t)gk*8 + myxcd)*64;
                    for (;;) {
                        int v = (tid < nloc)
                              ? __hip_atomic_load(ap + tid, __ATOMIC_RELAXED, __HIP_MEMORY_SCOPE_AGENT) : 1;
                        if (__all(v != 0)) break;
                        __builtin_amdgcn_s_sleep(1);
                    }
                }
                asm volatile("buffer_inv sc0 sc1\n\ts_waitcnt vmcnt(0)" ::: "memory");
                if (tid == 0)
                    __hip_atomic_store(invd, 1, __ATOMIC_RELAXED, __HIP_MEMORY_SCOPE_AGENT);
            } else {
                for (;;) {
                    int v = __hip_atomic_load(invd, __ATOMIC_RELAXED, __HIP_MEMORY_SCOPE_AGENT);
                    if (__all(v != 0)) break;
                    __builtin_amdgcn_s_sleep(1);
                }
                asm volatile("buffer_inv sc0\n\ts_waitcnt vmcnt(0)" ::: "memory");
            }
            const int* p0 = (tk >= 1) ? flg + ((size_t)stage*TICKS + tk-1)*64 : nullptr;
            const int* p1 = (tk >= 1) ? flg + ((size_t)(stage==0?3:stage-1)*TICKS + tk-1)*64 : nullptr;
            const int* p2 = (tk >= DD-1) ? flg + ((size_t)sN*TICKS + tk-DD+1)*64 : nullptr;
            for (;;) {
                int a = p0 ? __hip_atomic_load(p0 + tid, __ATOMIC_RELAXED, __HIP_MEMORY_SCOPE_AGENT) : 1;
                int b = p1 ? __hip_atomic_load(p1 + tid, __ATOMIC_RELAXED, __HIP_MEMORY_SCOPE_AGENT) : 1;
                int c = p2 ? __hip_atomic_load(p2 + tid, __ATOMIC_RELAXED, __HIP_MEMORY_SCOPE_AGENT) : 1;
                if (__all(a && b && c)) break;
                __builtin_amdgcn_s_sleep(1);
            }
        }
        __syncthreads();

        // ---- DMA-staged GEMM phases ----
        if (stage == 0) {
            const char* glh = (const char*)hb
                + (((size_t)(0*DD + rp))*BB + r0row) * 2048 + lco;
            const char* glf = (const char*)hb
                + (((size_t)(3*DD + rp))*BB + frow0 + lrow) * 2048 + lco;
            if (doH && doF)
                gemm_dma<true >(glh, glf, wbuf, img_b, img_fc, lane, acc0, acc1);
            else if (doH)
                gemm_dma<false>(glh, glh, wbuf, img_b, img_b, lane, acc0, acc1);
            else if (doF)
                gemm_dma<false>(glf, glf, wbuf, img_fc, img_fc, lane, acc1, acc0);
        } else if (doH) {
            const char* gl1 = (const char*)hb
                + (((size_t)((stage-1)*DD + rp))*BB + r0row) * 2048 + lco;
            const char* gl2 = (const char*)hb
                + (((size_t)((stage  )*DD + rp))*BB + r0row) * 2048 + lco;
            gemm_dma<true>(gl1, gl2, wbuf, img_a, img_b, lane, acc0, acc1);
        }

        if (doH) {
            __bf16* hq = hb + (size_t)(stage*DD + wq) * (BB*HH);
            #pragma unroll
            for (int j = 0; j < 4; ++j) {
                int m = 16 * wave + rb + j;
                float s = (stage == 0) ? acc0[j] : (acc0[j] + acc1[j]);
                store_h_wt(hq + (size_t)m*HH + bcol, tanh_fast(s + bi));
            }
        }
        if (doF) {
            const int t4 = tk - 4;
            #pragma unroll
            for (int j = 0; j < 4; ++j) {
                int b = frow0 + rb + j;
                store_f_wt(out + ((size_t)b*TT + t4)*OO + fcol, acc1[j] + fbias);
            }
        }

        __syncthreads();   // drains vmcnt (WT stores + DMA) before publish
        if (tid == 0)
            __hip_atomic_store(flg + ((size_t)stage*TICKS + tk)*64 + tile, 1,
                               __ATOMIC_RELAXED, __HIP_MEMORY_SCOPE_AGENT);
    }
}

extern "C" void kernel_launch(void* const* d_in, const int* in_sizes, int n_in,
                              void* d_out, int out_size, void* d_ws, size_t ws_size,
                              hipStream_t stream) {
    const float* x     = (const float*)d_in[0];
    const float* W_ih0 = (const float*)d_in[1];
    const float* b_ih0 = (const float*)d_in[2];
    const float* W_hh0 = (const float*)d_in[3];
    const float* b_hh0 = (const float*)d_in[4];
    const float* W_ih  = (const float*)d_in[5];
    const float* b_ih  = (const float*)d_in[6];
    const float* W_hh  = (const float*)d_in[7];
    const float* b_hh  = (const float*)d_in[8];
    const float* W_fc  = (const float*)d_in[9];
    const float* b_fc  = (const float*)d_in[10];
    float* outp = (float*)d_out;
    char*  wsp  = (char*)d_ws;

    static int lds_attr_set = 0;     // host-side only; idempotent
    if (!lds_attr_set) {
        hipFuncSetAttribute((const void*)rnn_coop<8>,
                            hipFuncAttributeMaxDynamicSharedMemorySize, LDS_BYTES);
        hipFuncSetAttribute((const void*)rnn_coop<2>,
                            hipFuncAttributeMaxDynamicSharedMemorySize, LDS_BYTES);
        lds_attr_set = 1;
    }

    void* args[] = { &x, &W_ih0, &b_ih0, &W_hh0, &b_hh0,
                     &W_ih, &b_ih, &W_hh, &b_hh, &W_fc, &b_fc,
                     &outp, &wsp };

    if (ws_size >= WS<8>::END) {
        hipMemsetAsync(d_ws, 0, WS<8>::END, stream);
        hipLaunchCooperativeKernel((const void*)rnn_coop<8>, dim3(256), dim3(512),
                                   args, LDS_BYTES, stream);
    } else if (ws_size >= WS<2>::END) {
        hipMemsetAsync(d_ws, 0, WS<2>::END, stream);
        hipLaunchCooperativeKernel((const void*)rnn_coop<2>, dim3(256), dim3(512),
                                   args, LDS_BYTES, stream);
    }
    // else: leave out untouched (diagnostic stub error)
}

// Round 12
// 11321.789 us; speedup vs baseline: 1.4045x; 1.4045x over previous
//
#include <hip/hip_runtime.h>

typedef __bf16 bf16x8  __attribute__((ext_vector_type(8)));
typedef float  f32x4   __attribute__((ext_vector_type(4)));

#define MFMA16(a,b,c) __builtin_amdgcn_mfma_f32_16x16x32_bf16((a),(b),(c),0,0,0)

constexpr int BB = 128, TT = 512, II = 512, HH = 1024, OO = 512;
constexpr int TICKS = TT + 4;
constexpr int LDS_BYTES = 81920;   // stage0: 16K wih0 + 32K whh0 + 32K wfc

// -------- workspace layout (bytes), ring depth DD (R9 layout, verbatim) ----
template<int DD> struct WS {
    static constexpr size_t HB      = (size_t)4*DD*BB*HH*2;
    static constexpr size_t FLG_OFF = HB;
    static constexpr size_t FLG     = (size_t)4*TICKS*64*4;
    static constexpr size_t ARR_OFF = FLG_OFF + FLG;
    static constexpr size_t ARR     = (size_t)TICKS*8*64*4;
    static constexpr size_t INV_OFF = ARR_OFF + ARR;
    static constexpr size_t INV     = (size_t)TICKS*8*64;
    static constexpr size_t CE_OFF  = INV_OFF + INV;
    static constexpr size_t IB_OFF  = CE_OFF + 64;
    static constexpr size_t END     = IB_OFF + 9*64;
};

__device__ __forceinline__ float tanh_fast(float v) {
    float e = __expf(2.0f * v);
    return 1.0f - 2.0f / (e + 1.0f);
}

__device__ __forceinline__ bf16x8 cvt8(const float* __restrict__ p) {
    float4 a = *(const float4*)p;
    float4 b = *(const float4*)(p + 4);
    bf16x8 r;
    r[0]=(__bf16)a.x; r[1]=(__bf16)a.y; r[2]=(__bf16)a.z; r[3]=(__bf16)a.w;
    r[4]=(__bf16)b.x; r[5]=(__bf16)b.y; r[6]=(__bf16)b.z; r[7]=(__bf16)b.w;
    return r;
}

// write-through system-scope stores (coherent at L3; L2 never dirty)
__device__ __forceinline__ void store_h_wt(__bf16* p, float v) {
    __bf16 b = (__bf16)v;
    unsigned u = *(unsigned short*)&b;
    asm volatile("global_store_short %0, %1, off sc0 sc1" :: "v"(p), "v"(u) : "memory");
}
__device__ __forceinline__ void store_f_wt(float* p, float v) {
    asm volatile("global_store_dword %0, %1, off sc0 sc1" :: "v"(p), "v"(v) : "memory");
}

__device__ __forceinline__ void stage_img(char* dst, const float* __restrict__ W,
                                          int Kdim, int col0, int tid) {
    const int nch = (Kdim / 32) * 64;
    for (int c = tid; c < nch; c += 512) {
        int i  = c >> 6, ln = c & 63;
        int col = col0 + (ln & 15);
        int k0  = i * 32 + ((ln >> 4) << 3);
        bf16x8 v = cvt8(W + (size_t)col * Kdim + k0);
        *(bf16x8*)(dst + (size_t)c * 16) = v;
    }
}

// x-path (f32, K=512): plain compiler path; latency overlaps the flag polls
template<int NITER, int CH>
__device__ __forceinline__ void gemm_x(const float* __restrict__ ap,
                                       const char* bimg, int lane, f32x4& acc) {
    const char* bp = bimg + (size_t)lane * 16;
    #pragma unroll 1
    for (int c = 0; c < NITER / CH; ++c) {
        bf16x8 B[CH], A[CH];
        #pragma unroll
        for (int j = 0; j < CH; ++j)
            B[j] = *(const bf16x8*)(bp + (size_t)(c*CH + j) * 1024);
        #pragma unroll
        for (int j = 0; j < CH; ++j)
            A[j] = cvt8(ap + (c*CH + j) * 32);
        #pragma unroll
        for (int j = 0; j < CH; ++j)
            acc = MFMA16(A[j], B[j], acc);
    }
}

// ---- compiler-safe MLP: keep-alive pin forces loads to stay clustered ----
#define PIN8(A) asm volatile("" :: "v"(A[0]),"v"(A[1]),"v"(A[2]),"v"(A[3]), \
                                   "v"(A[4]),"v"(A[5]),"v"(A[6]),"v"(A[7]))

template<bool TWO>
__device__ __forceinline__ void chunk_load(bf16x8 (&A0)[8], bf16x8 (&A1)[8],
                                           const __bf16* a0p, const __bf16* a1p,
                                           int c) {
    #pragma unroll
    for (int j = 0; j < 8; ++j) {
        A0[j] = *(const bf16x8*)(a0p + (c*8 + j) * 32);
        if constexpr (TWO) A1[j] = *(const bf16x8*)(a1p + (c*8 + j) * 32);
    }
}

template<bool TWO>
__device__ __forceinline__ void chunk_pin(const bf16x8 (&A0)[8], const bf16x8 (&A1)[8]) {
    PIN8(A0);
    if constexpr (TWO) PIN8(A1);
}

template<bool TWO>
__device__ __forceinline__ void chunk_mfma(const bf16x8 (&A0)[8], const bf16x8 (&A1)[8],
                                           const char* bp0, const char* bp1, int c,
                                           f32x4& acc0, f32x4& acc1) {
    #pragma unroll
    for (int j = 0; j < 8; ++j) {
        bf16x8 b0 = *(const bf16x8*)(bp0 + (size_t)(c*8 + j) * 1024);
        acc0 = MFMA16(A0[j], b0, acc0);
        if constexpr (TWO) {
            bf16x8 b1 = *(const bf16x8*)(bp1 + (size_t)(c*8 + j) * 1024);
            acc1 = MFMA16(A1[j], b1, acc1);
        }
    }
}

// K=1024 (32 k-steps) as 4 chunks of 8, double-buffered:
// [load c+1] SB [mfma c] [pin c+1]  ->  16 loads in flight under each MFMA block
template<bool TWO>
__device__ __forceinline__ void gemm_pin(const __bf16* a0p, const __bf16* a1p,
                                         const char* img0, const char* img1,
                                         int lane, f32x4& acc0, f32x4& acc1) {
    const char* bp0 = img0 + (size_t)lane * 16;
    const char* bp1 = img1 + (size_t)lane * 16;
    bf16x8 Xa[8], Ya[8], Xb[8], Yb[8];

    chunk_load<TWO>(Xa, Ya, a0p, a1p, 0);
    chunk_pin<TWO>(Xa, Ya);

    chunk_load<TWO>(Xb, Yb, a0p, a1p, 1);
    __builtin_amdgcn_sched_barrier(0);
    chunk_mfma<TWO>(Xa, Ya, bp0, bp1, 0, acc0, acc1);
    chunk_pin<TWO>(Xb, Yb);

    chunk_load<TWO>(Xa, Ya, a0p, a1p, 2);
    __builtin_amdgcn_sched_barrier(0);
    chunk_mfma<TWO>(Xb, Yb, bp0, bp1, 1, acc0, acc1);
    chunk_pin<TWO>(Xa, Ya);

    chunk_load<TWO>(Xb, Yb, a0p, a1p, 3);
    __builtin_amdgcn_sched_barrier(0);
    chunk_mfma<TWO>(Xa, Ya, bp0, bp1, 2, acc0, acc1);
    chunk_pin<TWO>(Xb, Yb);

    chunk_mfma<TWO>(Xb, Yb, bp0, bp1, 3, acc0, acc1);
}

template<int DD>
__device__ __forceinline__ void init_barrier(char* wsb, int grp, int tid) {
    __threadfence();
    __syncthreads();
    if (tid == 0) {
        int* c1 = (int*)(wsb + WS<DD>::IB_OFF + (size_t)grp * 64);
        int* c2 = (int*)(wsb + WS<DD>::IB_OFF + 8 * 64);
        int v = __hip_atomic_fetch_add(c1, 1, __ATOMIC_ACQ_REL, __HIP_MEMORY_SCOPE_AGENT);
        if (v == 31)
            __hip_atomic_fetch_add(c2, 1, __ATOMIC_ACQ_REL, __HIP_MEMORY_SCOPE_AGENT);
        while (__hip_atomic_load(c2, __ATOMIC_RELAXED, __HIP_MEMORY_SCOPE_AGENT) < 8)
            __builtin_amdgcn_s_sleep(2);
    }
    __syncthreads();
    __threadfence();
}

template<int DD>
__global__ void __launch_bounds__(512, 1)
rnn_coop(const float* __restrict__ x,
         const float* __restrict__ W_ih0, const float* __restrict__ b_ih0,
         const float* __restrict__ W_hh0, const float* __restrict__ b_hh0,
         const float* __restrict__ W_ih,  const float* __restrict__ b_ih,
         const float* __restrict__ W_hh,  const float* __restrict__ b_hh,
         const float* __restrict__ W_fc,  const float* __restrict__ b_fc,
         float* __restrict__ out, char* __restrict__ wsb)
{
    extern __shared__ char smem[];
    __shared__ int sh_slot, sh_n;

    const int blk = blockIdx.x, tid = threadIdx.x;
    const int wave = tid >> 6, lane = tid & 63;
    const int lrow = lane & 15;
    const int kg8  = (lane >> 4) << 3;
    const int rb   = (lane >> 4) << 2;

    int myxcd;
    asm volatile("s_getreg_b32 %0, hwreg(HW_REG_XCC_ID)" : "=s"(myxcd));
    myxcd &= 7;

    if (tid == 0)
        sh_slot = __hip_atomic_fetch_add((int*)(wsb + WS<DD>::CE_OFF) + myxcd, 1,
                                         __ATOMIC_RELAXED, __HIP_MEMORY_SCOPE_AGENT);

    const int stage = (blk & 7) >> 1;
    const int tile  = (blk >> 3) | ((blk & 1) << 5);
    const int N0    = tile * 16;

    char* img_a  = smem;
    char* img_b;
    char* img_fc = smem + 49152;
    if (stage == 0) {
        img_b = smem + 16384;
        stage_img(img_a, W_ih0, II, N0, tid);
        stage_img(img_b, W_hh0, HH, N0, tid);
        stage_img(img_fc, W_fc, HH, (tile & 31) * 16, tid);
    } else {
        img_b = smem + 32768;
        stage_img(img_a, W_ih + (size_t)(stage-1)*HH*HH, HH, N0, tid);
        stage_img(img_b, W_hh + (size_t)(stage-1)*HH*HH, HH, N0, tid);
    }

    const int bcol = N0 + lrow;
    float bi;
    if (stage == 0) bi = b_ih0[bcol] + b_hh0[bcol];
    else            bi = b_ih[(stage-1)*HH + bcol] + b_hh[(stage-1)*HH + bcol];

    const int fcol  = (tile & 31) * 16 + lrow;
    const int frow0 = (tile >> 5) * 64 + 16 * wave;
    const float fbias = (stage == 0) ? b_fc[fcol] : 0.f;

    const int r0row = 16 * wave + lrow;
    __bf16* hb = (__bf16*)wsb;
    int* flg = (int*)(wsb + WS<DD>::FLG_OFF);
    int* arr = (int*)(wsb + WS<DD>::ARR_OFF);

    __syncthreads();
    init_barrier<DD>(wsb, blk & 7, tid);
    if (tid == 0)
        sh_n = __hip_atomic_load((int*)(wsb + WS<DD>::CE_OFF) + myxcd,
                                 __ATOMIC_RELAXED, __HIP_MEMORY_SCOPE_AGENT);
    __syncthreads();
    const int slot = sh_slot, nloc = sh_n;
    const bool leader = (slot == 0);
    const int sN = (stage < 3) ? stage + 1 : 0;

    for (int tk = 0; tk < TICKS; ++tk) {
        const int rp = (tk - 1) & (DD - 1);
        const int wq = tk & (DD - 1);
        const int t  = tk - stage;
        const bool doH = (t >= 0 && t < TT);
        const bool doF = (stage == 0) && (wave < 4) && (tk >= 4);

        f32x4 acc0 = {0.f,0.f,0.f,0.f};
        f32x4 acc1 = {0.f,0.f,0.f,0.f};

        // x-GEMM is flag-independent: run BEFORE polls (latency overlaps wait)
        if (stage == 0 && doH) {
            const float* xa = x + (size_t)r0row * (TT*II) + (size_t)t * II + kg8;
            gemm_x<II/32, 4>(xa, img_a, lane, acc0);
        }

        // ---- protocol (R9-verbatim): arrival, per-XCD inv, dataflow polls ----
        if (tid == 0)
            __hip_atomic_store(arr + ((size_t)tk*8 + myxcd)*64 + slot, 1,
                               __ATOMIC_RELAXED, __HIP_MEMORY_SCOPE_AGENT);
        if (tid < 64) {
            int* invd = (int*)(wsb + WS<DD>::INV_OFF) + ((size_t)tk*8 + myxcd)*16;
            if (leader) {
                const int gk = tk - DD + 1;
                if (gk >= 0) {
                    int* ap = arr + ((size_t)gk*8 + myxcd)*64;
                    for (;;) {
                        int v = (tid < nloc)
                              ? __hip_atomic_load(ap + tid, __ATOMIC_RELAXED, __HIP_MEMORY_SCOPE_AGENT) : 1;
                        if (__all(v != 0)) break;
                        __builtin_amdgcn_s_sleep(1);
                    }
                }
                asm volatile("buffer_inv sc0 sc1\n\ts_waitcnt vmcnt(0)" ::: "memory");
                if (tid == 0)
                    __hip_atomic_store(invd, 1, __ATOMIC_RELAXED, __HIP_MEMORY_SCOPE_AGENT);
            } else {
                for (;;) {
                    int v = __hip_atomic_load(invd, __ATOMIC_RELAXED, __HIP_MEMORY_SCOPE_AGENT);
                    if (__all(v != 0)) break;
                    __builtin_amdgcn_s_sleep(1);
                }
                asm volatile("buffer_inv sc0\n\ts_waitcnt vmcnt(0)" ::: "memory");
            }
            const int* p0 = (tk >= 1) ? flg + ((size_t)stage*TICKS + tk-1)*64 : nullptr;
            const int* p1 = (tk >= 1) ? flg + ((size_t)(stage==0?3:stage-1)*TICKS + tk-1)*64 : nullptr;
            const int* p2 = (tk >= DD-1) ? flg + ((size_t)sN*TICKS + tk-DD+1)*64 : nullptr;
            for (;;) {
                int a = p0 ? __hip_atomic_load(p0 + tid, __ATOMIC_RELAXED, __HIP_MEMORY_SCOPE_AGENT) : 1;
                int b = p1 ? __hip_atomic_load(p1 + tid, __ATOMIC_RELAXED, __HIP_MEMORY_SCOPE_AGENT) : 1;
                int c = p2 ? __hip_atomic_load(p2 + tid, __ATOMIC_RELAXED, __HIP_MEMORY_SCOPE_AGENT) : 1;
                if (__all(a && b && c)) break;
                __builtin_amdgcn_s_sleep(1);
            }
        }
        __syncthreads();

        // ---- pinned-MLP GEMM phases ----
        if (stage == 0) {
            const __bf16* glh = hb + (((size_t)(0*DD + rp))*BB + r0row) * HH + kg8;
            const __bf16* glf = hb + (((size_t)(3*DD + rp))*BB + frow0 + lrow) * HH + kg8;
            if (doH && doF)
                gemm_pin<true >(glh, glf, img_b, img_fc, lane, acc0, acc1);
            else if (doH)
                gemm_pin<false>(glh, glh, img_b, img_b, lane, acc0, acc1);
            else if (doF)
                gemm_pin<false>(glf, glf, img_fc, img_fc, lane, acc1, acc0);
        } else if (doH) {
            const __bf16* a1 = hb + (((size_t)((stage-1)*DD + rp))*BB + r0row) * HH + kg8;
            const __bf16* a2 = hb + (((size_t)((stage  )*DD + rp))*BB + r0row) * HH + kg8;
            gemm_pin<true>(a1, a2, img_a, img_b, lane, acc0, acc1);
        }

        if (doH) {
            __bf16* hq = hb + (size_t)(stage*DD + wq) * (BB*HH);
            #pragma unroll
            for (int j = 0; j < 4; ++j) {
                int m = 16 * wave + rb + j;
                float s = (stage == 0) ? acc0[j] : (acc0[j] + acc1[j]);
                store_h_wt(hq + (size_t)m*HH + bcol, tanh_fast(s + bi));
            }
        }
        if (doF) {
            const int t4 = tk - 4;
            #pragma unroll
            for (int j = 0; j < 4; ++j) {
                int b = frow0 + rb + j;
                store_f_wt(out + ((size_t)b*TT + t4)*OO + fcol, acc1[j] + fbias);
            }
        }

        __syncthreads();   // drains vmcnt (WT stores) before publish
        if (tid == 0)
            __hip_atomic_store(flg + ((size_t)stage*TICKS + tk)*64 + tile, 1,
                               __ATOMIC_RELAXED, __HIP_MEMORY_SCOPE_AGENT);
    }
}

extern "C" void kernel_launch(void* const* d_in, const int* in_sizes, int n_in,
                              void* d_out, int out_size, void* d_ws, size_t ws_size,
                              hipStream_t stream) {
    const float* x     = (const float*)d_in[0];
    const float* W_ih0 = (const float*)d_in[1];
    const float* b_ih0 = (const float*)d_in[2];
    const float* W_hh0 = (const float*)d_in[3];
    const float* b_hh0 = (const float*)d_in[4];
    const float* W_ih  = (const float*)d_in[5];
    const float* b_ih  = (const float*)d_in[6];
    const float* W_hh  = (const float*)d_in[7];
    const float* b_hh  = (const float*)d_in[8];
    const float* W_fc  = (const float*)d_in[9];
    const float* b_fc  = (const float*)d_in[10];
    float* outp = (float*)d_out;
    char*  wsp  = (char*)d_ws;

    static int lds_attr_set = 0;     // host-side only; idempotent
    if (!lds_attr_set) {
        hipFuncSetAttribute((const void*)rnn_coop<8>,
                            hipFuncAttributeMaxDynamicSharedMemorySize, LDS_BYTES);
        hipFuncSetAttribute((const void*)rnn_coop<2>,
                            hipFuncAttributeMaxDynamicSharedMemorySize, LDS_BYTES);
        lds_attr_set = 1;
    }

    void* args[] = { &x, &W_ih0, &b_ih0, &W_hh0, &b_hh0,
                     &W_ih, &b_ih, &W_hh, &b_hh, &W_fc, &b_fc,
                     &outp, &wsp };

    if (ws_size >= WS<8>::END) {
        hipMemsetAsync(d_ws, 0, WS<8>::END, stream);
        hipLaunchCooperativeKernel((const void*)rnn_coop<8>, dim3(256), dim3(512),
                                   args, LDS_BYTES, stream);
    } else if (ws_size >= WS<2>::END) {
        hipMemsetAsync(d_ws, 0, WS<2>::END, stream);
        hipLaunchCooperativeKernel((const void*)rnn_coop<2>, dim3(256), dim3(512),
                                   args, LDS_BYTES, stream);
    }
    // else: leave out untouched (diagnostic stub error)
}

// Round 13
// 11273.184 us; speedup vs baseline: 1.4106x; 1.0043x over previous
//
#include <hip/hip_runtime.h>

typedef __bf16 bf16x8  __attribute__((ext_vector_type(8)));
typedef float  f32x4   __attribute__((ext_vector_type(4)));

#define MFMA16(a,b,c) __builtin_amdgcn_mfma_f32_16x16x32_bf16((a),(b),(c),0,0,0)

constexpr int BB = 128, TT = 512, II = 512, HH = 1024, OO = 512;
constexpr int TICKS = TT + 4;
constexpr int LDS_BYTES = 81920;   // stage0: 16K wih0 + 32K whh0 + 32K wfc

// -------- workspace layout (bytes), ring depth DD (R9 layout, verbatim) ----
template<int DD> struct WS {
    static constexpr size_t HB      = (size_t)4*DD*BB*HH*2;
    static constexpr size_t FLG_OFF = HB;
    static constexpr size_t FLG     = (size_t)4*TICKS*64*4;
    static constexpr size_t ARR_OFF = FLG_OFF + FLG;
    static constexpr size_t ARR     = (size_t)TICKS*8*64*4;
    static constexpr size_t INV_OFF = ARR_OFF + ARR;
    static constexpr size_t INV     = (size_t)TICKS*8*64;
    static constexpr size_t CE_OFF  = INV_OFF + INV;
    static constexpr size_t IB_OFF  = CE_OFF + 64;
    static constexpr size_t END     = IB_OFF + 9*64;
};

__device__ __forceinline__ float tanh_fast(float v) {
    float e = __expf(2.0f * v);
    return 1.0f - 2.0f / (e + 1.0f);
}

__device__ __forceinline__ bf16x8 cvt8(const float* __restrict__ p) {
    float4 a = *(const float4*)p;
    float4 b = *(const float4*)(p + 4);
    bf16x8 r;
    r[0]=(__bf16)a.x; r[1]=(__bf16)a.y; r[2]=(__bf16)a.z; r[3]=(__bf16)a.w;
    r[4]=(__bf16)b.x; r[5]=(__bf16)b.y; r[6]=(__bf16)b.z; r[7]=(__bf16)b.w;
    return r;
}

// write-through system-scope stores (coherent at L3; L2 never dirty)
__device__ __forceinline__ void store_h_wt(__bf16* p, float v) {
    __bf16 b = (__bf16)v;
    unsigned u = *(unsigned short*)&b;
    asm volatile("global_store_short %0, %1, off sc0 sc1" :: "v"(p), "v"(u) : "memory");
}
__device__ __forceinline__ void store_f_wt(float* p, float v) {
    asm volatile("global_store_dword %0, %1, off sc0 sc1" :: "v"(p), "v"(v) : "memory");
}

__device__ __forceinline__ void stage_img(char* dst, const float* __restrict__ W,
                                          int Kdim, int col0, int tid) {
    const int nch = (Kdim / 32) * 64;
    for (int c = tid; c < nch; c += 512) {
        int i  = c >> 6, ln = c & 63;
        int col = col0 + (ln & 15);
        int k0  = i * 32 + ((ln >> 4) << 3);
        bf16x8 v = cvt8(W + (size_t)col * Kdim + k0);
        *(bf16x8*)(dst + (size_t)c * 16) = v;
    }
}

// ================== compiler-proof MLP: inline-asm loads ==================
// Guards: "=&v" early-clobber dests; vmcnt(0) at entry; sched_barrier(0)
// after every counted wait (MFMA hoist fence, rule #18).

template<bool TWO>
__device__ __forceinline__ void issue_h(bf16x8 (&S0)[4], bf16x8 (&S1)[4],
                                        const __bf16* a0p, const __bf16* a1p, int c) {
    #pragma unroll
    for (int j = 0; j < 4; ++j) {
        asm volatile("global_load_dwordx4 %0, %1, off"
            : "=&v"(S0[j]) : "v"(a0p + (c*4 + j) * 32) : "memory");
        if constexpr (TWO)
            asm volatile("global_load_dwordx4 %0, %1, off"
                : "=&v"(S1[j]) : "v"(a1p + (c*4 + j) * 32) : "memory");
    }
}

// K=1024 (32 k-steps): 8 chunks of 4, 3 rotating buffers, 2 chunks prefetch
// => 8/16 loads in flight steady-state. Counted vmcnt exact: entry drains to
// 0 and only our asm loads issue VMEM inside.
template<bool TWO>
__device__ __forceinline__ void gemm_asm(const __bf16* a0p, const __bf16* a1p,
                                         const char* img0, const char* img1,
                                         int lane, f32x4& acc0, f32x4& acc1) {
    const char* bp0 = img0 + (size_t)lane * 16;
    const char* bp1 = img1 + (size_t)lane * 16;
    bf16x8 S0[3][4], S1[3][4];
    asm volatile("s_waitcnt vmcnt(0)" ::: "memory");
    __builtin_amdgcn_sched_barrier(0);
    issue_h<TWO>(S0[0], S1[0], a0p, a1p, 0);
    issue_h<TWO>(S0[1], S1[1], a0p, a1p, 1);
    #pragma unroll
    for (int c = 0; c < 8; ++c) {
        if (c < 6) issue_h<TWO>(S0[(c+2)%3], S1[(c+2)%3], a0p, a1p, c+2);
        if (c < 6) {
            if constexpr (TWO) asm volatile("s_waitcnt vmcnt(16)" ::: "memory");
            else               asm volatile("s_waitcnt vmcnt(8)"  ::: "memory");
        } else if (c == 6) {
            if constexpr (TWO) asm volatile("s_waitcnt vmcnt(8)" ::: "memory");
            else               asm volatile("s_waitcnt vmcnt(4)" ::: "memory");
        } else {
            asm volatile("s_waitcnt vmcnt(0)" ::: "memory");
        }
        __builtin_amdgcn_sched_barrier(0);
        #pragma unroll
        for (int j = 0; j < 4; ++j) {
            bf16x8 b0 = *(const bf16x8*)(bp0 + (size_t)(c*4 + j) * 1024);
            acc0 = MFMA16(S0[c%3][j], b0, acc0);
            if constexpr (TWO) {
                bf16x8 b1 = *(const bf16x8*)(bp1 + (size_t)(c*4 + j) * 1024);
                acc1 = MFMA16(S1[c%3][j], b1, acc1);
            }
        }
    }
}

// x-path (f32, K=512): same machinery; 4 chunks of 4 k-steps, 8 loads/chunk.
__device__ __forceinline__ void issue_x(f32x4 (&S)[8], const float* ap, int c) {
    #pragma unroll
    for (int j = 0; j < 4; ++j) {
        asm volatile("global_load_dwordx4 %0, %1, off"
            : "=&v"(S[2*j])   : "v"(ap + (c*4 + j) * 32)     : "memory");
        asm volatile("global_load_dwordx4 %0, %1, off"
            : "=&v"(S[2*j+1]) : "v"(ap + (c*4 + j) * 32 + 4) : "memory");
    }
}
__device__ __forceinline__ bf16x8 pack8(const f32x4& a, const f32x4& b) {
    bf16x8 r;
    r[0]=(__bf16)a[0]; r[1]=(__bf16)a[1]; r[2]=(__bf16)a[2]; r[3]=(__bf16)a[3];
    r[4]=(__bf16)b[0]; r[5]=(__bf16)b[1]; r[6]=(__bf16)b[2]; r[7]=(__bf16)b[3];
    return r;
}
__device__ __forceinline__ void gemm_x_asm(const float* ap, const char* img0,
                                           int lane, f32x4& acc) {
    const char* bp = img0 + (size_t)lane * 16;
    f32x4 S[3][8];
    asm volatile("s_waitcnt vmcnt(0)" ::: "memory");
    __builtin_amdgcn_sched_barrier(0);
    issue_x(S[0], ap, 0);
    issue_x(S[1], ap, 1);
    #pragma unroll
    for (int c = 0; c < 4; ++c) {
        if (c < 2) issue_x(S[(c+2)%3], ap, c+2);
        if (c < 2)      asm volatile("s_waitcnt vmcnt(16)" ::: "memory");
        else if (c==2)  asm volatile("s_waitcnt vmcnt(8)"  ::: "memory");
        else            asm volatile("s_waitcnt vmcnt(0)"  ::: "memory");
        __builtin_amdgcn_sched_barrier(0);
        #pragma unroll
        for (int j = 0; j < 4; ++j) {
            bf16x8 a = pack8(S[c%3][2*j], S[c%3][2*j+1]);
            bf16x8 b = *(const bf16x8*)(bp + (size_t)(c*4 + j) * 1024);
            acc = MFMA16(a, b, acc);
        }
    }
}

template<int DD>
__device__ __forceinline__ void init_barrier(char* wsb, int grp, int tid) {
    __threadfence();
    __syncthreads();
    if (tid == 0) {
        int* c1 = (int*)(wsb + WS<DD>::IB_OFF + (size_t)grp * 64);
        int* c2 = (int*)(wsb + WS<DD>::IB_OFF + 8 * 64);
        int v = __hip_atomic_fetch_add(c1, 1, __ATOMIC_ACQ_REL, __HIP_MEMORY_SCOPE_AGENT);
        if (v == 31)
            __hip_atomic_fetch_add(c2, 1, __ATOMIC_ACQ_REL, __HIP_MEMORY_SCOPE_AGENT);
        while (__hip_atomic_load(c2, __ATOMIC_RELAXED, __HIP_MEMORY_SCOPE_AGENT) < 8)
            __builtin_amdgcn_s_sleep(2);
    }
    __syncthreads();
    __threadfence();
}

template<int DD>
__global__ void __launch_bounds__(512, 1)
rnn_coop(const float* __restrict__ x,
         const float* __restrict__ W_ih0, const float* __restrict__ b_ih0,
         const float* __restrict__ W_hh0, const float* __restrict__ b_hh0,
         const float* __restrict__ W_ih,  const float* __restrict__ b_ih,
         const float* __restrict__ W_hh,  const float* __restrict__ b_hh,
         const float* __restrict__ W_fc,  const float* __restrict__ b_fc,
         float* __restrict__ out, char* __restrict__ wsb)
{
    extern __shared__ char smem[];
    __shared__ int sh_slot, sh_n;

    const int blk = blockIdx.x, tid = threadIdx.x;
    const int wave = tid >> 6, lane = tid & 63;
    const int lrow = lane & 15;
    const int kg8  = (lane >> 4) << 3;
    const int rb   = (lane >> 4) << 2;

    int myxcd;
    asm volatile("s_getreg_b32 %0, hwreg(HW_REG_XCC_ID)" : "=s"(myxcd));
    myxcd &= 7;

    if (tid == 0)
        sh_slot = __hip_atomic_fetch_add((int*)(wsb + WS<DD>::CE_OFF) + myxcd, 1,
                                         __ATOMIC_RELAXED, __HIP_MEMORY_SCOPE_AGENT);

    const int stage = (blk & 7) >> 1;
    const int tile  = (blk >> 3) | ((blk & 1) << 5);
    const int N0    = tile * 16;

    char* img_a  = smem;
    char* img_b;
    char* img_fc = smem + 49152;
    if (stage == 0) {
        img_b = smem + 16384;
        stage_img(img_a, W_ih0, II, N0, tid);
        stage_img(img_b, W_hh0, HH, N0, tid);
        stage_img(img_fc, W_fc, HH, (tile & 31) * 16, tid);
    } else {
        img_b = smem + 32768;
        stage_img(img_a, W_ih + (size_t)(stage-1)*HH*HH, HH, N0, tid);
        stage_img(img_b, W_hh + (size_t)(stage-1)*HH*HH, HH, N0, tid);
    }

    const int bcol = N0 + lrow;
    float bi;
    if (stage == 0) bi = b_ih0[bcol] + b_hh0[bcol];
    else            bi = b_ih[(stage-1)*HH + bcol] + b_hh[(stage-1)*HH + bcol];

    const int fcol  = (tile & 31) * 16 + lrow;
    const int frow0 = (tile >> 5) * 64 + 16 * wave;
    const float fbias = (stage == 0) ? b_fc[fcol] : 0.f;

    const int r0row = 16 * wave + lrow;
    __bf16* hb = (__bf16*)wsb;
    int* flg = (int*)(wsb + WS<DD>::FLG_OFF);
    int* arr = (int*)(wsb + WS<DD>::ARR_OFF);

    __syncthreads();
    init_barrier<DD>(wsb, blk & 7, tid);
    if (tid == 0)
        sh_n = __hip_atomic_load((int*)(wsb + WS<DD>::CE_OFF) + myxcd,
                                 __ATOMIC_RELAXED, __HIP_MEMORY_SCOPE_AGENT);
    __syncthreads();
    const int slot = sh_slot, nloc = sh_n;
    const bool leader = (slot == 0);
    const int sN = (stage < 3) ? stage + 1 : 0;

    for (int tk = 0; tk < TICKS; ++tk) {
        const int rp = (tk - 1) & (DD - 1);
        const int wq = tk & (DD - 1);
        const int t  = tk - stage;
        const bool doH = (t >= 0 && t < TT);
        const bool doF = (stage == 0) && (wave < 4) && (tk >= 4);

        f32x4 acc0 = {0.f,0.f,0.f,0.f};
        f32x4 acc1 = {0.f,0.f,0.f,0.f};

        // x-GEMM is flag-independent: run BEFORE polls, now MLP-pipelined
        if (stage == 0 && doH) {
            const float* xa = x + (size_t)r0row * (TT*II) + (size_t)t * II + kg8;
            gemm_x_asm(xa, img_a, lane, acc0);
        }

        // ---- protocol (R9-verbatim): arrival, per-XCD inv, dataflow polls ----
        if (tid == 0)
            __hip_atomic_store(arr + ((size_t)tk*8 + myxcd)*64 + slot, 1,
                               __ATOMIC_RELAXED, __HIP_MEMORY_SCOPE_AGENT);
        if (tid < 64) {
            int* invd = (int*)(wsb + WS<DD>::INV_OFF) + ((size_t)tk*8 + myxcd)*16;
            if (leader) {
                const int gk = tk - DD + 1;
                if (gk >= 0) {
                    int* ap = arr + ((size_t)gk*8 + myxcd)*64;
                    for (;;) {
                        int v = (tid < nloc)
                              ? __hip_atomic_load(ap + tid, __ATOMIC_RELAXED, __HIP_MEMORY_SCOPE_AGENT) : 1;
                        if (__all(v != 0)) break;
                        __builtin_amdgcn_s_sleep(1);
                    }
                }
                asm volatile("buffer_inv sc0 sc1\n\ts_waitcnt vmcnt(0)" ::: "memory");
                if (tid == 0)
                    __hip_atomic_store(invd, 1, __ATOMIC_RELAXED, __HIP_MEMORY_SCOPE_AGENT);
            } else {
                for (;;) {
                    int v = __hip_atomic_load(invd, __ATOMIC_RELAXED, __HIP_MEMORY_SCOPE_AGENT);
                    if (__all(v != 0)) break;
                    __builtin_amdgcn_s_sleep(1);
                }
                asm volatile("buffer_inv sc0\n\ts_waitcnt vmcnt(0)" ::: "memory");
            }
            const int* p0 = (tk >= 1) ? flg + ((size_t)stage*TICKS + tk-1)*64 : nullptr;
            const int* p1 = (tk >= 1) ? flg + ((size_t)(stage==0?3:stage-1)*TICKS + tk-1)*64 : nullptr;
            const int* p2 = (tk >= DD-1) ? flg + ((size_t)sN*TICKS + tk-DD+1)*64 : nullptr;
            for (;;) {
                int a = p0 ? __hip_atomic_load(p0 + tid, __ATOMIC_RELAXED, __HIP_MEMORY_SCOPE_AGENT) : 1;
                int b = p1 ? __hip_atomic_load(p1 + tid, __ATOMIC_RELAXED, __HIP_MEMORY_SCOPE_AGENT) : 1;
                int c = p2 ? __hip_atomic_load(p2 + tid, __ATOMIC_RELAXED, __HIP_MEMORY_SCOPE_AGENT) : 1;
                if (__all(a && b && c)) break;
                __builtin_amdgcn_s_sleep(1);
            }
        }
        __syncthreads();

        // ---- asm-MLP GEMM phases ----
        if (stage == 0) {
            const __bf16* glh = hb + (((size_t)(0*DD + rp))*BB + r0row) * HH + kg8;
            const __bf16* glf = hb + (((size_t)(3*DD + rp))*BB + frow0 + lrow) * HH + kg8;
            if (doH && doF)
                gemm_asm<true >(glh, glf, img_b, img_fc, lane, acc0, acc1);
            else if (doH)
                gemm_asm<false>(glh, glh, img_b, img_b, lane, acc0, acc1);
            else if (doF)
                gemm_asm<false>(glf, glf, img_fc, img_fc, lane, acc1, acc0);
        } else if (doH) {
            const __bf16* a1 = hb + (((size_t)((stage-1)*DD + rp))*BB + r0row) * HH + kg8;
            const __bf16* a2 = hb + (((size_t)((stage  )*DD + rp))*BB + r0row) * HH + kg8;
            gemm_asm<true>(a1, a2, img_a, img_b, lane, acc0, acc1);
        }

        if (doH) {
            __bf16* hq = hb + (size_t)(stage*DD + wq) * (BB*HH);
            #pragma unroll
            for (int j = 0; j < 4; ++j) {
                int m = 16 * wave + rb + j;
                float s = (stage == 0) ? acc0[j] : (acc0[j] + acc1[j]);
                store_h_wt(hq + (size_t)m*HH + bcol, tanh_fast(s + bi));
            }
        }
        if (doF) {
            const int t4 = tk - 4;
            #pragma unroll
            for (int j = 0; j < 4; ++j) {
                int b = frow0 + rb + j;
                store_f_wt(out + ((size_t)b*TT + t4)*OO + fcol, acc1[j] + fbias);
            }
        }

        // explicit per-wave drain: all WT stores acked before flag publish
        asm volatile("s_waitcnt vmcnt(0)" ::: "memory");
        __syncthreads();
        if (tid == 0)
            __hip_atomic_store(flg + ((size_t)stage*TICKS + tk)*64 + tile, 1,
                               __ATOMIC_RELAXED, __HIP_MEMORY_SCOPE_AGENT);
    }
}

extern "C" void kernel_launch(void* const* d_in, const int* in_sizes, int n_in,
                              void* d_out, int out_size, void* d_ws, size_t ws_size,
                              hipStream_t stream) {
    const float* x     = (const float*)d_in[0];
    const float* W_ih0 = (const float*)d_in[1];
    const float* b_ih0 = (const float*)d_in[2];
    const float* W_hh0 = (const float*)d_in[3];
    const float* b_hh0 = (const float*)d_in[4];
    const float* W_ih  = (const float*)d_in[5];
    const float* b_ih  = (const float*)d_in[6];
    const float* W_hh  = (const float*)d_in[7];
    const float* b_hh  = (const float*)d_in[8];
    const float* W_fc  = (const float*)d_in[9];
    const float* b_fc  = (const float*)d_in[10];
    float* outp = (float*)d_out;
    char*  wsp  = (char*)d_ws;

    static int lds_attr_set = 0;     // host-side only; idempotent
    if (!lds_attr_set) {
        hipFuncSetAttribute((const void*)rnn_coop<8>,
                            hipFuncAttributeMaxDynamicSharedMemorySize, LDS_BYTES);
        hipFuncSetAttribute((const void*)rnn_coop<2>,
                            hipFuncAttributeMaxDynamicSharedMemorySize, LDS_BYTES);
        lds_attr_set = 1;
    }

    void* args[] = { &x, &W_ih0, &b_ih0, &W_hh0, &b_hh0,
                     &W_ih, &b_ih, &W_hh, &b_hh, &W_fc, &b_fc,
                     &outp, &wsp };

    if (ws_size >= WS<8>::END) {
        hipMemsetAsync(d_ws, 0, WS<8>::END, stream);
        hipLaunchCooperativeKernel((const void*)rnn_coop<8>, dim3(256), dim3(512),
                                   args, LDS_BYTES, stream);
    } else if (ws_size >= WS<2>::END) {
        hipMemsetAsync(d_ws, 0, WS<2>::END, stream);
        hipLaunchCooperativeKernel((const void*)rnn_coop<2>, dim3(256), dim3(512),
                                   args, LDS_BYTES, stream);
    }
    // else: leave out untouched (diagnostic stub error)
}

// Round 15
// 11168.721 us; speedup vs baseline: 1.4237x; 1.0094x over previous
//
#include <hip/hip_runtime.h>

typedef __bf16 bf16x8  __attribute__((ext_vector_type(8)));
typedef float  f32x4   __attribute__((ext_vector_type(4)));

#define MFMA16(a,b,c) __builtin_amdgcn_mfma_f32_16x16x32_bf16((a),(b),(c),0,0,0)

constexpr int BB = 128, TT = 512, II = 512, HH = 1024, OO = 512;
constexpr int TICKS = TT + 4;
constexpr int DD = 8;              // h ring depth
constexpr int LDS_BYTES = 81920;   // stage0: 16K wih0 + 32K whh0 + 32K wfc

// -------- workspace layout (bytes) — R13 layout --------
struct WS {
    static constexpr size_t HB      = (size_t)4*DD*BB*HH*2;
    static constexpr size_t FLG_OFF = HB;
    static constexpr size_t FLG     = (size_t)4*TICKS*64*4;
    static constexpr size_t ARR_OFF = FLG_OFF + FLG;
    static constexpr size_t ARR     = (size_t)TICKS*8*64*4;
    static constexpr size_t INV_OFF = ARR_OFF + ARR;
    static constexpr size_t INV     = (size_t)TICKS*8*64;
    static constexpr size_t CE_OFF  = INV_OFF + INV;
    static constexpr size_t IB_OFF  = CE_OFF + 64;
    static constexpr size_t END     = IB_OFF + 9*64;
};

__device__ __forceinline__ float tanh_fast(float v) {
    float e = __expf(2.0f * v);
    return 1.0f - 2.0f / (e + 1.0f);
}

__device__ __forceinline__ bf16x8 cvt8(const float* __restrict__ p) {
    float4 a = *(const float4*)p;
    float4 b = *(const float4*)(p + 4);
    bf16x8 r;
    r[0]=(__bf16)a.x; r[1]=(__bf16)a.y; r[2]=(__bf16)a.z; r[3]=(__bf16)a.w;
    r[4]=(__bf16)b.x; r[5]=(__bf16)b.y; r[6]=(__bf16)b.z; r[7]=(__bf16)b.w;
    return r;
}

// write-through system-scope stores (coherent at L3; L2 never dirty)
__device__ __forceinline__ void store_h_wt(__bf16* p, float v) {
    __bf16 b = (__bf16)v;
    unsigned u = *(unsigned short*)&b;
    asm volatile("global_store_short %0, %1, off sc0 sc1" :: "v"(p), "v"(u) : "memory");
}
__device__ __forceinline__ void store_f_wt(float* p, float v) {
    asm volatile("global_store_dword %0, %1, off sc0 sc1" :: "v"(p), "v"(v) : "memory");
}

__device__ __forceinline__ void stage_img(char* dst, const float* __restrict__ W,
                                          int Kdim, int col0, int tid) {
    const int nch = (Kdim / 32) * 64;
    for (int c = tid; c < nch; c += 512) {
        int i  = c >> 6, ln = c & 63;
        int col = col0 + (ln & 15);
        int k0  = i * 32 + ((ln >> 4) << 3);
        bf16x8 v = cvt8(W + (size_t)col * Kdim + k0);
        *(bf16x8*)(dst + (size_t)c * 16) = v;
    }
}

// ================== R13-proven asm-MLP GEMMs (unchanged) ==================
template<bool TWO>
__device__ __forceinline__ void issue_h(bf16x8 (&S0)[4], bf16x8 (&S1)[4],
                                        const __bf16* a0p, const __bf16* a1p, int c) {
    #pragma unroll
    for (int j = 0; j < 4; ++j) {
        asm volatile("global_load_dwordx4 %0, %1, off"
            : "=&v"(S0[j]) : "v"(a0p + (c*4 + j) * 32) : "memory");
        if constexpr (TWO)
            asm volatile("global_load_dwordx4 %0, %1, off"
                : "=&v"(S1[j]) : "v"(a1p + (c*4 + j) * 32) : "memory");
    }
}

template<bool TWO>
__device__ __forceinline__ void gemm_asm(const __bf16* a0p, const __bf16* a1p,
                                         const char* img0, const char* img1,
                                         int lane, f32x4& acc0, f32x4& acc1) {
    const char* bp0 = img0 + (size_t)lane * 16;
    const char* bp1 = img1 + (size_t)lane * 16;
    bf16x8 S0[3][4], S1[3][4];
    asm volatile("s_waitcnt vmcnt(0)" ::: "memory");
    __builtin_amdgcn_sched_barrier(0);
    issue_h<TWO>(S0[0], S1[0], a0p, a1p, 0);
    issue_h<TWO>(S0[1], S1[1], a0p, a1p, 1);
    #pragma unroll
    for (int c = 0; c < 8; ++c) {
        if (c < 6) issue_h<TWO>(S0[(c+2)%3], S1[(c+2)%3], a0p, a1p, c+2);
        if (c < 6) {
            if constexpr (TWO) asm volatile("s_waitcnt vmcnt(16)" ::: "memory");
            else               asm volatile("s_waitcnt vmcnt(8)"  ::: "memory");
        } else if (c == 6) {
            if constexpr (TWO) asm volatile("s_waitcnt vmcnt(8)" ::: "memory");
            else               asm volatile("s_waitcnt vmcnt(4)" ::: "memory");
        } else {
            asm volatile("s_waitcnt vmcnt(0)" ::: "memory");
        }
        __builtin_amdgcn_sched_barrier(0);
        #pragma unroll
        for (int j = 0; j < 4; ++j) {
            bf16x8 b0 = *(const bf16x8*)(bp0 + (size_t)(c*4 + j) * 1024);
            acc0 = MFMA16(S0[c%3][j], b0, acc0);
            if constexpr (TWO) {
                bf16x8 b1 = *(const bf16x8*)(bp1 + (size_t)(c*4 + j) * 1024);
                acc1 = MFMA16(S1[c%3][j], b1, acc1);
            }
        }
    }
}

__device__ __forceinline__ void issue_x(f32x4 (&S)[8], const float* ap, int c) {
    #pragma unroll
    for (int j = 0; j < 4; ++j) {
        asm volatile("global_load_dwordx4 %0, %1, off"
            : "=&v"(S[2*j])   : "v"(ap + (c*4 + j) * 32)     : "memory");
        asm volatile("global_load_dwordx4 %0, %1, off"
            : "=&v"(S[2*j+1]) : "v"(ap + (c*4 + j) * 32 + 4) : "memory");
    }
}
__device__ __forceinline__ bf16x8 pack8(const f32x4& a, const f32x4& b) {
    bf16x8 r;
    r[0]=(__bf16)a[0]; r[1]=(__bf16)a[1]; r[2]=(__bf16)a[2]; r[3]=(__bf16)a[3];
    r[4]=(__bf16)b[0]; r[5]=(__bf16)b[1]; r[6]=(__bf16)b[2]; r[7]=(__bf16)b[3];
    return r;
}
__device__ __forceinline__ void gemm_x_asm(const float* ap, const char* img0,
                                           int lane, f32x4& acc) {
    const char* bp = img0 + (size_t)lane * 16;
    f32x4 S[3][8];
    asm volatile("s_waitcnt vmcnt(0)" ::: "memory");
    __builtin_amdgcn_sched_barrier(0);
    issue_x(S[0], ap, 0);
    issue_x(S[1], ap, 1);
    #pragma unroll
    for (int c = 0; c < 4; ++c) {
        if (c < 2) issue_x(S[(c+2)%3], ap, c+2);
        if (c < 2)      asm volatile("s_waitcnt vmcnt(16)" ::: "memory");
        else if (c==2)  asm volatile("s_waitcnt vmcnt(8)"  ::: "memory");
        else            asm volatile("s_waitcnt vmcnt(0)"  ::: "memory");
        __builtin_amdgcn_sched_barrier(0);
        #pragma unroll
        for (int j = 0; j < 4; ++j) {
            bf16x8 a = pack8(S[c%3][2*j], S[c%3][2*j+1]);
            bf16x8 b = *(const bf16x8*)(bp + (size_t)(c*4 + j) * 1024);
            acc = MFMA16(a, b, acc);
        }
    }
}

__device__ __forceinline__ void init_barrier(char* wsb, int grp, int tid) {
    __threadfence();
    __syncthreads();
    if (tid == 0) {
        int* c1 = (int*)(wsb + WS::IB_OFF + (size_t)grp * 64);
        int* c2 = (int*)(wsb + WS::IB_OFF + 8 * 64);
        int v = __hip_atomic_fetch_add(c1, 1, __ATOMIC_ACQ_REL, __HIP_MEMORY_SCOPE_AGENT);
        if (v == 31)
            __hip_atomic_fetch_add(c2, 1, __ATOMIC_ACQ_REL, __HIP_MEMORY_SCOPE_AGENT);
        while (__hip_atomic_load(c2, __ATOMIC_RELAXED, __HIP_MEMORY_SCOPE_AGENT) < 8)
            __builtin_amdgcn_s_sleep(2);
    }
    __syncthreads();
    __threadfence();
}

__global__ void __launch_bounds__(512, 1)
rnn_coop(const float* __restrict__ x,
         const float* __restrict__ W_ih0, const float* __restrict__ b_ih0,
         const float* __restrict__ W_hh0, const float* __restrict__ b_hh0,
         const float* __restrict__ W_ih,  const float* __restrict__ b_ih,
         const float* __restrict__ W_hh,  const float* __restrict__ b_hh,
         const float* __restrict__ W_fc,  const float* __restrict__ b_fc,
         float* __restrict__ out, char* __restrict__ wsb)
{
    extern __shared__ char smem[];
    __shared__ int sh_slot, sh_n;

    const int blk = blockIdx.x, tid = threadIdx.x;
    const int wave = tid >> 6, lane = tid & 63;
    const int lrow = lane & 15;
    const int kg8  = (lane >> 4) << 3;
    const int rb   = (lane >> 4) << 2;

    int myxcd;
    asm volatile("s_getreg_b32 %0, hwreg(HW_REG_XCC_ID)" : "=s"(myxcd));
    myxcd &= 7;

    if (tid == 0)
        sh_slot = __hip_atomic_fetch_add((int*)(wsb + WS::CE_OFF) + myxcd, 1,
                                         __ATOMIC_RELAXED, __HIP_MEMORY_SCOPE_AGENT);

    const int stage = (blk & 7) >> 1;
    const int tile  = (blk >> 3) | ((blk & 1) << 5);
    const int N0    = tile * 16;

    char* img_a  = smem;
    char* img_b;
    char* img_fc = smem + 49152;
    if (stage == 0) {
        img_b = smem + 16384;
        stage_img(img_a, W_ih0, II, N0, tid);
        stage_img(img_b, W_hh0, HH, N0, tid);
        stage_img(img_fc, W_fc, HH, (tile & 31) * 16, tid);
    } else {
        img_b = smem + 32768;
        stage_img(img_a, W_ih + (size_t)(stage-1)*HH*HH, HH, N0, tid);
        stage_img(img_b, W_hh + (size_t)(stage-1)*HH*HH, HH, N0, tid);
    }

    const int bcol = N0 + lrow;
    float bi;
    if (stage == 0) bi = b_ih0[bcol] + b_hh0[bcol];
    else            bi = b_ih[(stage-1)*HH + bcol] + b_hh[(stage-1)*HH + bcol];

    const int fcol  = (tile & 31) * 16 + lrow;
    const int frow0 = (tile >> 5) * 64 + 16 * wave;
    const float fbias = (stage == 0) ? b_fc[fcol] : 0.f;

    const int r0row = 16 * wave + lrow;
    __bf16* hb = (__bf16*)wsb;
    int* flg = (int*)(wsb + WS::FLG_OFF);
    int* arr = (int*)(wsb + WS::ARR_OFF);

    __syncthreads();
    init_barrier(wsb, blk & 7, tid);
    if (tid == 0)
        sh_n = __hip_atomic_load((int*)(wsb + WS::CE_OFF) + myxcd,
                                 __ATOMIC_RELAXED, __HIP_MEMORY_SCOPE_AGENT);
    __syncthreads();
    const int slot = sh_slot, nloc = sh_n;
    const bool leader = (slot == 0);

    // prologue: x@W_ih0 contribution for t=0 (stage 0), carried in xacc
    f32x4 xacc = {0.f,0.f,0.f,0.f};
    if (stage == 0) {
        const float* xa = x + (size_t)r0row * (TT*II) + kg8;
        gemm_x_asm(xa, img_a, lane, xacc);
    }

    for (int tk = 0; tk < TICKS; ++tk) {
        const int rp = (tk - 1) & (DD - 1);
        const int wq = tk & (DD - 1);
        const int t  = tk - stage;
        const bool doH = (t >= 0 && t < TT);

        f32x4 acc0 = {0.f,0.f,0.f,0.f};
        f32x4 accW = {0.f,0.f,0.f,0.f};
        if (stage == 0 && doH) acc0 = xacc;   // x contribution (same acc order as R13)

        // ---- protocol (R13-verbatim): arrival, per-XCD gated inv, polls ----
        if (tid == 0)
            __hip_atomic_store(arr + ((size_t)tk*8 + myxcd)*64 + slot, 1,
                               __ATOMIC_RELAXED, __HIP_MEMORY_SCOPE_AGENT);
        if (tid < 64) {
            int* invd = (int*)(wsb + WS::INV_OFF) + ((size_t)tk*8 + myxcd)*16;
            if (leader) {
                const int gk = tk - DD + 1;
                if (gk >= 0) {
                    int* ap = arr + ((size_t)gk*8 + myxcd)*64;
                    for (;;) {
                        int v = (tid < nloc)
                              ? __hip_atomic_load(ap + tid, __ATOMIC_RELAXED, __HIP_MEMORY_SCOPE_AGENT) : 1;
                        if (__all(v != 0)) break;
                        __builtin_amdgcn_s_sleep(1);
                    }
                }
                asm volatile("buffer_inv sc0 sc1\n\ts_waitcnt vmcnt(0)" ::: "memory");
                if (tid == 0)
                    __hip_atomic_store(invd, 1, __ATOMIC_RELAXED, __HIP_MEMORY_SCOPE_AGENT);
            } else {
                for (;;) {
                    int v = __hip_atomic_load(invd, __ATOMIC_RELAXED, __HIP_MEMORY_SCOPE_AGENT);
                    if (__all(v != 0)) break;
                    __builtin_amdgcn_s_sleep(1);
                }
                asm volatile("buffer_inv sc0\n\ts_waitcnt vmcnt(0)" ::: "memory");
            }
            // p0: own-stage RAW (tk-1); p1: upstream RAW (stage0: h3 for FC);
            // p2: WAR — stage<3: downstream reads @tk-7; stage3: FC done => flg[0][tk-6]
            const int* p0 = (tk >= 1) ? flg + ((size_t)stage*TICKS + tk-1)*64 : nullptr;
            const int* p1 = (tk >= 1) ? flg + ((size_t)(stage==0?3:stage-1)*TICKS + tk-1)*64 : nullptr;
            const int* p2 = nullptr;
            if (stage < 3) { if (tk >= DD-1) p2 = flg + ((size_t)(stage+1)*TICKS + tk-DD+1)*64; }
            else           { if (tk >= DD-2) p2 = flg + ((size_t)0*TICKS + tk-DD+2)*64; }
            for (;;) {
                int a = p0 ? __hip_atomic_load(p0 + tid, __ATOMIC_RELAXED, __HIP_MEMORY_SCOPE_AGENT) : 1;
                int b = p1 ? __hip_atomic_load(p1 + tid, __ATOMIC_RELAXED, __HIP_MEMORY_SCOPE_AGENT) : 1;
                int c = p2 ? __hip_atomic_load(p2 + tid, __ATOMIC_RELAXED, __HIP_MEMORY_SCOPE_AGENT) : 1;
                if (__all(a && b && c)) break;
                __builtin_amdgcn_s_sleep(1);
            }
        }
        __syncthreads();

        // ---- recurrence GEMMs (asm-MLP, R13-verbatim mechanics) ----
        if (doH) {
            const __bf16* aown = hb + (((size_t)(stage*DD + rp))*BB + r0row) * HH + kg8;
            if (stage == 0) {
                gemm_asm<false>(aown, aown, img_b, img_b, lane, acc0, accW);
            } else {
                gemm_asm<false>(aown, aown, img_b, img_b, lane, accW, acc0);  // W_hh
                const __bf16* aup = hb + (((size_t)((stage-1)*DD + rp))*BB + r0row) * HH + kg8;
                gemm_asm<false>(aup, aup, img_a, img_a, lane, acc0, accW);    // W_ih
            }
            __bf16* hq = hb + (size_t)(stage*DD + wq) * (BB*HH);
            #pragma unroll
            for (int j = 0; j < 4; ++j) {
                int m = 16 * wave + rb + j;
                float s = (stage == 0) ? acc0[j] : (acc0[j] + accW[j]);
                store_h_wt(hq + (size_t)m*HH + bcol, tanh_fast(s + bi));
            }
            asm volatile("s_waitcnt vmcnt(0)" ::: "memory");   // h stores acked
        }

        __syncthreads();                    // all waves' h drained
        if (tid == 0)                       // EARLY publish (before FC / x-pre)
            __hip_atomic_store(flg + ((size_t)stage*TICKS + tk)*64 + tile, 1,
                               __ATOMIC_RELAXED, __HIP_MEMORY_SCOPE_AGENT);

        // ---- off-chain work: FC (waves 0-3) + next-tick x-GEMM precompute ----
        if (stage == 0) {
            if (wave < 4 && tk >= 4) {      // h3(tk-1) gated by p1 this tick
                f32x4 fa = {0.f,0.f,0.f,0.f}, dmy = {0.f,0.f,0.f,0.f};
                const __bf16* glf = hb + (((size_t)(3*DD + rp))*BB + frow0 + lrow) * HH + kg8;
                gemm_asm<false>(glf, glf, img_fc, img_fc, lane, fa, dmy);
                const int t4 = tk - 4;
                #pragma unroll
                for (int j = 0; j < 4; ++j) {
                    int b = frow0 + rb + j;
                    store_f_wt(out + ((size_t)b*TT + t4)*OO + fcol, fa[j] + fbias);
                }
            }
            if (tk + 1 < TT) {              // precompute x@W_ih0 for t = tk+1
                xacc[0]=0.f; xacc[1]=0.f; xacc[2]=0.f; xacc[3]=0.f;
                const float* xa = x + (size_t)r0row * (TT*II) + (size_t)(tk+1) * II + kg8;
                gemm_x_asm(xa, img_a, lane, xacc);
            }
        }
    }
}

extern "C" void kernel_launch(void* const* d_in, const int* in_sizes, int n_in,
                              void* d_out, int out_size, void* d_ws, size_t ws_size,
                              hipStream_t stream) {
    const float* x     = (const float*)d_in[0];
    const float* W_ih0 = (const float*)d_in[1];
    const float* b_ih0 = (const float*)d_in[2];
    const float* W_hh0 = (const float*)d_in[3];
    const float* b_hh0 = (const float*)d_in[4];
    const float* W_ih  = (const float*)d_in[5];
    const float* b_ih  = (const float*)d_in[6];
    const float* W_hh  = (const float*)d_in[7];
    const float* b_hh  = (const float*)d_in[8];
    const float* W_fc  = (const float*)d_in[9];
    const float* b_fc  = (const float*)d_in[10];
    float* outp = (float*)d_out;
    char*  wsp  = (char*)d_ws;

    if (ws_size < WS::END) return;   // diagnostic gate (stub error if too small)

    static int lds_attr_set = 0;     // host-side only; idempotent
    if (!lds_attr_set) {
        hipFuncSetAttribute((const void*)rnn_coop,
                            hipFuncAttributeMaxDynamicSharedMemorySize, LDS_BYTES);
        lds_attr_set = 1;
    }

    hipMemsetAsync(d_ws, 0, WS::END, stream);

    void* args[] = { &x, &W_ih0, &b_ih0, &W_hh0, &b_hh0,
                     &W_ih, &b_ih, &W_hh, &b_hh, &W_fc, &b_fc,
                     &outp, &wsp };
    hipLaunchCooperativeKernel((const void*)rnn_coop, dim3(256), dim3(512),
                               args, LDS_BYTES, stream);
}

// Round 16
// 10830.733 us; speedup vs baseline: 1.4682x; 1.0312x over previous
//
#include <hip/hip_runtime.h>

typedef __bf16 bf16x8  __attribute__((ext_vector_type(8)));
typedef float  f32x4   __attribute__((ext_vector_type(4)));

#define MFMA16(a,b,c) __builtin_amdgcn_mfma_f32_16x16x32_bf16((a),(b),(c),0,0,0)

constexpr int BB = 128, TT = 512, II = 512, HH = 1024, OO = 512;
constexpr int TICKS = TT + 4;
constexpr int DD = 8;              // h ring depth
constexpr int LDS_BYTES = 81920;   // stage0: 16K wih0 + 32K whh0 + 32K wfc

// -------- workspace layout (bytes) — R13/R15 layout (ARR kept, unused) ----
struct WS {
    static constexpr size_t HB      = (size_t)4*DD*BB*HH*2;
    static constexpr size_t FLG_OFF = HB;
    static constexpr size_t FLG     = (size_t)4*TICKS*64*4;
    static constexpr size_t ARR_OFF = FLG_OFF + FLG;
    static constexpr size_t ARR     = (size_t)TICKS*8*64*4;
    static constexpr size_t INV_OFF = ARR_OFF + ARR;
    static constexpr size_t INV     = (size_t)TICKS*8*64;
    static constexpr size_t CE_OFF  = INV_OFF + INV;
    static constexpr size_t IB_OFF  = CE_OFF + 64;
    static constexpr size_t END     = IB_OFF + 9*64;
};

__device__ __forceinline__ float tanh_fast(float v) {
    float e = __expf(2.0f * v);
    return 1.0f - 2.0f / (e + 1.0f);
}

__device__ __forceinline__ bf16x8 cvt8(const float* __restrict__ p) {
    float4 a = *(const float4*)p;
    float4 b = *(const float4*)(p + 4);
    bf16x8 r;
    r[0]=(__bf16)a.x; r[1]=(__bf16)a.y; r[2]=(__bf16)a.z; r[3]=(__bf16)a.w;
    r[4]=(__bf16)b.x; r[5]=(__bf16)b.y; r[6]=(__bf16)b.z; r[7]=(__bf16)b.w;
    return r;
}

// write-through system-scope stores (coherent at L3; L2 never dirty)
__device__ __forceinline__ void store_h_wt(__bf16* p, float v) {
    __bf16 b = (__bf16)v;
    unsigned u = *(unsigned short*)&b;
    asm volatile("global_store_short %0, %1, off sc0 sc1" :: "v"(p), "v"(u) : "memory");
}
__device__ __forceinline__ void store_f_wt(float* p, float v) {
    asm volatile("global_store_dword %0, %1, off sc0 sc1" :: "v"(p), "v"(v) : "memory");
}

__device__ __forceinline__ void stage_img(char* dst, const float* __restrict__ W,
                                          int Kdim, int col0, int tid) {
    const int nch = (Kdim / 32) * 64;
    for (int c = tid; c < nch; c += 512) {
        int i  = c >> 6, ln = c & 63;
        int col = col0 + (ln & 15);
        int k0  = i * 32 + ((ln >> 4) << 3);
        bf16x8 v = cvt8(W + (size_t)col * Kdim + k0);
        *(bf16x8*)(dst + (size_t)c * 16) = v;
    }
}

// ================== R13-proven asm-MLP GEMMs (unchanged) ==================
template<bool TWO>
__device__ __forceinline__ void issue_h(bf16x8 (&S0)[4], bf16x8 (&S1)[4],
                                        const __bf16* a0p, const __bf16* a1p, int c) {
    #pragma unroll
    for (int j = 0; j < 4; ++j) {
        asm volatile("global_load_dwordx4 %0, %1, off"
            : "=&v"(S0[j]) : "v"(a0p + (c*4 + j) * 32) : "memory");
        if constexpr (TWO)
            asm volatile("global_load_dwordx4 %0, %1, off"
                : "=&v"(S1[j]) : "v"(a1p + (c*4 + j) * 32) : "memory");
    }
}

template<bool TWO>
__device__ __forceinline__ void gemm_asm(const __bf16* a0p, const __bf16* a1p,
                                         const char* img0, const char* img1,
                                         int lane, f32x4& acc0, f32x4& acc1) {
    const char* bp0 = img0 + (size_t)lane * 16;
    const char* bp1 = img1 + (size_t)lane * 16;
    bf16x8 S0[3][4], S1[3][4];
    asm volatile("s_waitcnt vmcnt(0)" ::: "memory");
    __builtin_amdgcn_sched_barrier(0);
    issue_h<TWO>(S0[0], S1[0], a0p, a1p, 0);
    issue_h<TWO>(S0[1], S1[1], a0p, a1p, 1);
    #pragma unroll
    for (int c = 0; c < 8; ++c) {
        if (c < 6) issue_h<TWO>(S0[(c+2)%3], S1[(c+2)%3], a0p, a1p, c+2);
        if (c < 6) {
            if constexpr (TWO) asm volatile("s_waitcnt vmcnt(16)" ::: "memory");
            else               asm volatile("s_waitcnt vmcnt(8)"  ::: "memory");
        } else if (c == 6) {
            if constexpr (TWO) asm volatile("s_waitcnt vmcnt(8)" ::: "memory");
            else               asm volatile("s_waitcnt vmcnt(4)" ::: "memory");
        } else {
            asm volatile("s_waitcnt vmcnt(0)" ::: "memory");
        }
        __builtin_amdgcn_sched_barrier(0);
        #pragma unroll
        for (int j = 0; j < 4; ++j) {
            bf16x8 b0 = *(const bf16x8*)(bp0 + (size_t)(c*4 + j) * 1024);
            acc0 = MFMA16(S0[c%3][j], b0, acc0);
            if constexpr (TWO) {
                bf16x8 b1 = *(const bf16x8*)(bp1 + (size_t)(c*4 + j) * 1024);
                acc1 = MFMA16(S1[c%3][j], b1, acc1);
            }
        }
    }
}

__device__ __forceinline__ void issue_x(f32x4 (&S)[8], const float* ap, int c) {
    #pragma unroll
    for (int j = 0; j < 4; ++j) {
        asm volatile("global_load_dwordx4 %0, %1, off"
            : "=&v"(S[2*j])   : "v"(ap + (c*4 + j) * 32)     : "memory");
        asm volatile("global_load_dwordx4 %0, %1, off"
            : "=&v"(S[2*j+1]) : "v"(ap + (c*4 + j) * 32 + 4) : "memory");
    }
}
__device__ __forceinline__ bf16x8 pack8(const f32x4& a, const f32x4& b) {
    bf16x8 r;
    r[0]=(__bf16)a[0]; r[1]=(__bf16)a[1]; r[2]=(__bf16)a[2]; r[3]=(__bf16)a[3];
    r[4]=(__bf16)b[0]; r[5]=(__bf16)b[1]; r[6]=(__bf16)b[2]; r[7]=(__bf16)b[3];
    return r;
}
__device__ __forceinline__ void gemm_x_asm(const float* ap, const char* img0,
                                           int lane, f32x4& acc) {
    const char* bp = img0 + (size_t)lane * 16;
    f32x4 S[3][8];
    asm volatile("s_waitcnt vmcnt(0)" ::: "memory");
    __builtin_amdgcn_sched_barrier(0);
    issue_x(S[0], ap, 0);
    issue_x(S[1], ap, 1);
    #pragma unroll
    for (int c = 0; c < 4; ++c) {
        if (c < 2) issue_x(S[(c+2)%3], ap, c+2);
        if (c < 2)      asm volatile("s_waitcnt vmcnt(16)" ::: "memory");
        else if (c==2)  asm volatile("s_waitcnt vmcnt(8)"  ::: "memory");
        else            asm volatile("s_waitcnt vmcnt(0)"  ::: "memory");
        __builtin_amdgcn_sched_barrier(0);
        #pragma unroll
        for (int j = 0; j < 4; ++j) {
            bf16x8 a = pack8(S[c%3][2*j], S[c%3][2*j+1]);
            bf16x8 b = *(const bf16x8*)(bp + (size_t)(c*4 + j) * 1024);
            acc = MFMA16(a, b, acc);
        }
    }
}

__device__ __forceinline__ void init_barrier(char* wsb, int grp, int tid) {
    __threadfence();
    __syncthreads();
    if (tid == 0) {
        int* c1 = (int*)(wsb + WS::IB_OFF + (size_t)grp * 64);
        int* c2 = (int*)(wsb + WS::IB_OFF + 8 * 64);
        int v = __hip_atomic_fetch_add(c1, 1, __ATOMIC_ACQ_REL, __HIP_MEMORY_SCOPE_AGENT);
        if (v == 31)
            __hip_atomic_fetch_add(c2, 1, __ATOMIC_ACQ_REL, __HIP_MEMORY_SCOPE_AGENT);
        while (__hip_atomic_load(c2, __ATOMIC_RELAXED, __HIP_MEMORY_SCOPE_AGENT) < 8)
            __builtin_amdgcn_s_sleep(2);
    }
    __syncthreads();
    __threadfence();
}

__global__ void __launch_bounds__(512, 1)
rnn_coop(const float* __restrict__ x,
         const float* __restrict__ W_ih0, const float* __restrict__ b_ih0,
         const float* __restrict__ W_hh0, const float* __restrict__ b_hh0,
         const float* __restrict__ W_ih,  const float* __restrict__ b_ih,
         const float* __restrict__ W_hh,  const float* __restrict__ b_hh,
         const float* __restrict__ W_fc,  const float* __restrict__ b_fc,
         float* __restrict__ out, char* __restrict__ wsb)
{
    extern __shared__ char smem[];
    __shared__ int sh_slot;

    const int blk = blockIdx.x, tid = threadIdx.x;
    const int wave = tid >> 6, lane = tid & 63;
    const int lrow = lane & 15;
    const int kg8  = (lane >> 4) << 3;
    const int rb   = (lane >> 4) << 2;

    int myxcd;
    asm volatile("s_getreg_b32 %0, hwreg(HW_REG_XCC_ID)" : "=s"(myxcd));
    myxcd &= 7;

    if (tid == 0)
        sh_slot = __hip_atomic_fetch_add((int*)(wsb + WS::CE_OFF) + myxcd, 1,
                                         __ATOMIC_RELAXED, __HIP_MEMORY_SCOPE_AGENT);

    const int stage = (blk & 7) >> 1;
    const int tile  = (blk >> 3) | ((blk & 1) << 5);
    const int N0    = tile * 16;

    char* img_a  = smem;
    char* img_b;
    char* img_fc = smem + 49152;
    if (stage == 0) {
        img_b = smem + 16384;
        stage_img(img_a, W_ih0, II, N0, tid);
        stage_img(img_b, W_hh0, HH, N0, tid);
        stage_img(img_fc, W_fc, HH, (tile & 31) * 16, tid);
    } else {
        img_b = smem + 32768;
        stage_img(img_a, W_ih + (size_t)(stage-1)*HH*HH, HH, N0, tid);
        stage_img(img_b, W_hh + (size_t)(stage-1)*HH*HH, HH, N0, tid);
    }

    const int bcol = N0 + lrow;
    float bi;
    if (stage == 0) bi = b_ih0[bcol] + b_hh0[bcol];
    else            bi = b_ih[(stage-1)*HH + bcol] + b_hh[(stage-1)*HH + bcol];

    const int fcol  = (tile & 31) * 16 + lrow;
    const int frow0 = (tile >> 5) * 64 + 16 * wave;
    const float fbias = (stage == 0) ? b_fc[fcol] : 0.f;

    const int r0row = 16 * wave + lrow;
    __bf16* hb = (__bf16*)wsb;
    int* flg = (int*)(wsb + WS::FLG_OFF);

    __syncthreads();
    init_barrier(wsb, blk & 7, tid);
    const bool leader = (sh_slot == 0);

    // prologue: x@W_ih0 contribution for t=0 (stage 0), carried in xacc
    f32x4 xacc = {0.f,0.f,0.f,0.f};
    if (stage == 0) {
        const float* xa = x + (size_t)r0row * (TT*II) + kg8;
        gemm_x_asm(xa, img_a, lane, xacc);
    }

    for (int tk = 0; tk < TICKS; ++tk) {
        const int rp = (tk - 1) & (DD - 1);
        const int wq = tk & (DD - 1);
        const int t  = tk - stage;
        const bool doH = (t >= 0 && t < TT);

        f32x4 acc0 = {0.f,0.f,0.f,0.f};
        f32x4 accW = {0.f,0.f,0.f,0.f};
        if (stage == 0 && doH) acc0 = xacc;   // x contribution (same acc order)

        // ---- protocol: per-LAP inv (WT stores -> L2 never dirty -> inv is
        // always safe; one inv per XCD per DD ticks covers every ring-slot
        // reuse) + per-tick dataflow polls (R15-verbatim p0/p1/p2) ----
        if (tid < 64) {
            if ((tk & (DD - 1)) == 0) {
                int* invd = (int*)(wsb + WS::INV_OFF) + ((size_t)tk*8 + myxcd)*16;
                if (leader) {
                    asm volatile("buffer_inv sc0 sc1\n\ts_waitcnt vmcnt(0)" ::: "memory");
                    if (tid == 0)
                        __hip_atomic_store(invd, 1, __ATOMIC_RELAXED, __HIP_MEMORY_SCOPE_AGENT);
                } else {
                    for (;;) {
                        int v = __hip_atomic_load(invd, __ATOMIC_RELAXED, __HIP_MEMORY_SCOPE_AGENT);
                        if (__all(v != 0)) break;
                        __builtin_amdgcn_s_sleep(1);
                    }
                    asm volatile("buffer_inv sc0\n\ts_waitcnt vmcnt(0)" ::: "memory");
                }
            }
            // p0: own-stage RAW (tk-1); p1: upstream RAW (stage0: h3 for FC);
            // p2: WAR — stage<3: downstream reads @tk-7; stage3: FC => flg[0][tk-6]
            const int* p0 = (tk >= 1) ? flg + ((size_t)stage*TICKS + tk-1)*64 : nullptr;
            const int* p1 = (tk >= 1) ? flg + ((size_t)(stage==0?3:stage-1)*TICKS + tk-1)*64 : nullptr;
            const int* p2 = nullptr;
            if (stage < 3) { if (tk >= DD-1) p2 = flg + ((size_t)(stage+1)*TICKS + tk-DD+1)*64; }
            else           { if (tk >= DD-2) p2 = flg + ((size_t)0*TICKS + tk-DD+2)*64; }
            for (;;) {
                int a = p0 ? __hip_atomic_load(p0 + tid, __ATOMIC_RELAXED, __HIP_MEMORY_SCOPE_AGENT) : 1;
                int b = p1 ? __hip_atomic_load(p1 + tid, __ATOMIC_RELAXED, __HIP_MEMORY_SCOPE_AGENT) : 1;
                int c = p2 ? __hip_atomic_load(p2 + tid, __ATOMIC_RELAXED, __HIP_MEMORY_SCOPE_AGENT) : 1;
                if (__all(a && b && c)) break;
                __builtin_amdgcn_s_sleep(1);
            }
        }
        __syncthreads();

        // ---- recurrence GEMMs (asm-MLP, R15-verbatim mechanics) ----
        if (doH) {
            const __bf16* aown = hb + (((size_t)(stage*DD + rp))*BB + r0row) * HH + kg8;
            if (stage == 0) {
                gemm_asm<false>(aown, aown, img_b, img_b, lane, acc0, accW);
            } else {
                gemm_asm<false>(aown, aown, img_b, img_b, lane, accW, acc0);  // W_hh
                const __bf16* aup = hb + (((size_t)((stage-1)*DD + rp))*BB + r0row) * HH + kg8;
                gemm_asm<false>(aup, aup, img_a, img_a, lane, acc0, accW);    // W_ih
            }
            __bf16* hq = hb + (size_t)(stage*DD + wq) * (BB*HH);
            #pragma unroll
            for (int j = 0; j < 4; ++j) {
                int m = 16 * wave + rb + j;
                float s = (stage == 0) ? acc0[j] : (acc0[j] + accW[j]);
                store_h_wt(hq + (size_t)m*HH + bcol, tanh_fast(s + bi));
            }
            asm volatile("s_waitcnt vmcnt(0)" ::: "memory");   // h stores acked
        }

        __syncthreads();                    // all waves' h drained
        if (tid == 0)                       // EARLY publish (before FC / x-pre)
            __hip_atomic_store(flg + ((size_t)stage*TICKS + tk)*64 + tile, 1,
                               __ATOMIC_RELAXED, __HIP_MEMORY_SCOPE_AGENT);

        // ---- off-chain work: FC (waves 0-3) + next-tick x-GEMM precompute ----
        if (stage == 0) {
            if (wave < 4 && tk >= 4) {      // h3(tk-1) gated by p1 this tick
                f32x4 fa = {0.f,0.f,0.f,0.f}, dmy = {0.f,0.f,0.f,0.f};
                const __bf16* glf = hb + (((size_t)(3*DD + rp))*BB + frow0 + lrow) * HH + kg8;
                gemm_asm<false>(glf, glf, img_fc, img_fc, lane, fa, dmy);
                const int t4 = tk - 4;
                #pragma unroll
                for (int j = 0; j < 4; ++j) {
                    int b = frow0 + rb + j;
                    store_f_wt(out + ((size_t)b*TT + t4)*OO + fcol, fa[j] + fbias);
                }
            }
            if (tk + 1 < TT) {              // precompute x@W_ih0 for t = tk+1
                xacc[0]=0.f; xacc[1]=0.f; xacc[2]=0.f; xacc[3]=0.f;
                const float* xa = x + (size_t)r0row * (TT*II) + (size_t)(tk+1) * II + kg8;
                gemm_x_asm(xa, img_a, lane, xacc);
            }
        }
    }
}

extern "C" void kernel_launch(void* const* d_in, const int* in_sizes, int n_in,
                              void* d_out, int out_size, void* d_ws, size_t ws_size,
                              hipStream_t stream) {
    const float* x     = (const float*)d_in[0];
    const float* W_ih0 = (const float*)d_in[1];
    const float* b_ih0 = (const float*)d_in[2];
    const float* W_hh0 = (const float*)d_in[3];
    const float* b_hh0 = (const float*)d_in[4];
    const float* W_ih  = (const float*)d_in[5];
    const float* b_ih  = (const float*)d_in[6];
    const float* W_hh  = (const float*)d_in[7];
    const float* b_hh  = (const float*)d_in[8];
    const float* W_fc  = (const float*)d_in[9];
    const float* b_fc  = (const float*)d_in[10];
    float* outp = (float*)d_out;
    char*  wsp  = (char*)d_ws;

    if (ws_size < WS::END) return;   // diagnostic gate (stub error if too small)

    static int lds_attr_set = 0;     // host-side only; idempotent
    if (!lds_attr_set) {
        hipFuncSetAttribute((const void*)rnn_coop,
                            hipFuncAttributeMaxDynamicSharedMemorySize, LDS_BYTES);
        lds_attr_set = 1;
    }

    hipMemsetAsync(d_ws, 0, WS::END, stream);

    void* args[] = { &x, &W_ih0, &b_ih0, &W_hh0, &b_hh0,
                     &W_ih, &b_ih, &W_hh, &b_hh, &W_fc, &b_fc,
                     &outp, &wsp };
    hipLaunchCooperativeKernel((const void*)rnn_coop, dim3(256), dim3(512),
                               args, LDS_BYTES, stream);
}